// Round 14
// baseline (376.748 us; speedup 1.0000x reference)
//
#include <hip/hip_runtime.h>

// Capsule routing: B=32, N_IN=2048, IN_DIM=32, N_OUT=64, OUT_DIM=32, 3 iterations.
#define NI   2048
#define NO   64
#define DD   32
#define ODIM 2048   // NO*DD, the fused (o,d) axis

typedef short bf16x8 __attribute__((ext_vector_type(8)));
typedef float f32x4  __attribute__((ext_vector_type(4)));
typedef unsigned int u32x2 __attribute__((ext_vector_type(2)));
typedef unsigned int u32x4 __attribute__((ext_vector_type(4)));

__device__ __forceinline__ unsigned int cvt_pk_bf16(float lo, float hi) {
  unsigned int r;
  asm("v_cvt_pk_bf16_f32 %0, %1, %2" : "=v"(r) : "v"(lo), "v"(hi));
  return r;
}
__device__ __forceinline__ float bflo(unsigned int u) { return __uint_as_float(u << 16); }
__device__ __forceinline__ float bfhi(unsigned int u) { return __uint_as_float(u & 0xffff0000u); }

union BFPack { unsigned int u[4]; bf16x8 v; };

// K1 (R14): u_hat[b][i][od] = sum_k W[o,i,d,k]*x[b,i,k], MFMA 16x16x32 bf16.
// Restructure vs R13: olds LDS transpose tile REMOVED — each wave stores its
// MFMA output directly to U (cached; L2 merges the 32-B lane-quad runs; this
// exact store pattern passed in R1/R2-cached). X double-buffered in
// xlds[2] (32 KB total). ONE __syncthreads per 8-i phase (was 2 + olds deps):
//   STAGE(p+1)->buf[(p+1)&1] (last read at phase p-1, barrier-separated)
//   CONSUME(p) reads buf[p&1] (staged at p-1, barrier-separated)
// LDS 53->32 KB: occupancy 3->4+ blocks/CU; barriers/block 8->4.
// W register pipeline (8 dwordx4 NT in flight, issue-ahead) kept from R13.
__global__ __launch_bounds__(256) void k1_uhat(
    const float* __restrict__ W, const float* __restrict__ X,
    unsigned short* __restrict__ U, float* __restrict__ part) {
  __shared__ __attribute__((aligned(16))) unsigned short xlds[2][8][32][32]; // 32,768 B
  const int tid   = threadIdx.x;
  const int lane  = tid & 63;
  const int w     = tid >> 6;
  const int ob    = blockIdx.x & 31;   // 64-od block
  const int ib    = blockIdx.x >> 5;   // i-block of 32
  const int odq   = (ob << 2) + w;     // 16-od strip
  const int o     = odq >> 1;          // output capsule
  const int db    = (odq & 1) << 4;    // d base within o
  const int row16 = lane & 15;         // A row within 16
  const int kg    = lane >> 4;         // k-group
  const int k0    = kg << 3;           // k offset (8 contiguous)
  const int crow  = kg << 2;           // C/D row base [m89 verified]
  const int ccol  = lane & 15;         // C/D col
  const int sb    = tid >> 3;          // stage: b (0..31)
  const int sii   = tid & 7;           // stage: i within phase (0..7)
  const int xslot = (kg ^ (ccol & 3)) << 3;  // swizzled k-slot for consume reads
  const int od    = (odq << 4) + crow; // this lane's 4 output od's (const)

  f32x4 sacc[2];
  sacc[0] = f32x4{0.f, 0.f, 0.f, 0.f};
  sacc[1] = f32x4{0.f, 0.f, 0.f, 0.f};

  const float* wbase = W + (((size_t)o * NI) << 10) + ((db + row16) << 5) + k0;

  // Stage X[all b][phase 8 i][all k] -> xlds[buf] bf16. One (b,i) row/thread.
  auto STAGE = [&](int p, int buf) {
    const int i = (ib << 5) + (p << 3) + sii;
    const float4* xp = (const float4*)(X + (((size_t)(sb * NI + i)) << 5));
    float4 xv[8];
#pragma unroll
    for (int j = 0; j < 8; ++j) xv[j] = xp[j];
#pragma unroll
    for (int j = 0; j < 4; ++j) {
      u32x4 pk;
      pk.x = cvt_pk_bf16(xv[2*j].x,   xv[2*j].y);
      pk.y = cvt_pk_bf16(xv[2*j].z,   xv[2*j].w);
      pk.z = cvt_pk_bf16(xv[2*j+1].x, xv[2*j+1].y);
      pk.w = cvt_pk_bf16(xv[2*j+1].z, xv[2*j+1].w);
      *(u32x4*)&xlds[buf][sii][sb][(j ^ (sb & 3)) << 3] = pk;
    }
  };

  // Issue W NT loads for a 4-i half-batch; pin the issue point.
  auto ISSUE = [&](int p, int h, f32x4* wa, f32x4* wb) {
    const int ia = (ib << 5) + (p << 3) + (h << 2);
#pragma unroll
    for (int j = 0; j < 4; ++j) {
      const f32x4* wp = (const f32x4*)(wbase + ((size_t)(ia + j) << 10));
      wa[j] = __builtin_nontemporal_load(wp);
      wb[j] = __builtin_nontemporal_load(wp + 1);
    }
    __builtin_amdgcn_sched_barrier(0);
  };

  // Consume a staged half-batch: A from W regs, B from xlds[buf], 2 MFMA,
  // store D directly to U (cached 8-B per lane; lane-quads form 32-B runs,
  // the 4 waves' strips tile 128 B per (b,i) -> L2 line merge).
  auto CONSUME = [&](int p, int buf, int h, const f32x4* wa, const f32x4* wb) {
#pragma unroll
    for (int j = 0; j < 4; ++j) {
      const int ii = (h << 2) + j;
      const int i  = (ib << 5) + (p << 3) + ii;
      bf16x8 bx0 = *(const bf16x8*)&xlds[buf][ii][ccol][xslot];
      bf16x8 bx1 = *(const bf16x8*)&xlds[buf][ii][ccol + 16][xslot];
      BFPack af;
      af.u[0] = cvt_pk_bf16(wa[j].x, wa[j].y);
      af.u[1] = cvt_pk_bf16(wa[j].z, wa[j].w);
      af.u[2] = cvt_pk_bf16(wb[j].x, wb[j].y);
      af.u[3] = cvt_pk_bf16(wb[j].z, wb[j].w);
      {
        f32x4 d = __builtin_amdgcn_mfma_f32_16x16x32_bf16(
            af.v, bx0, f32x4{0.f, 0.f, 0.f, 0.f}, 0, 0, 0);
        sacc[0] += d;
        u32x2 pk; pk.x = cvt_pk_bf16(d[0], d[1]); pk.y = cvt_pk_bf16(d[2], d[3]);
        *(u32x2*)(U + (((size_t)(ccol * NI + i)) << 11) + od) = pk;
      }
      {
        f32x4 d = __builtin_amdgcn_mfma_f32_16x16x32_bf16(
            af.v, bx1, f32x4{0.f, 0.f, 0.f, 0.f}, 0, 0, 0);
        sacc[1] += d;
        u32x2 pk; pk.x = cvt_pk_bf16(d[0], d[1]); pk.y = cvt_pk_bf16(d[2], d[3]);
        *(u32x2*)(U + (((size_t)((ccol + 16) * NI + i)) << 11) + od) = pk;
      }
    }
  };

  f32x4 wa0[4], wb0[4], wa1[4], wb1[4];
  STAGE(0, 0);
  ISSUE(0, 0, wa0, wb0);
  __syncthreads();                    // xlds[0] ready

  for (int p = 0; p < 4; ++p) {
    const int buf = p & 1;
    if (p < 3) STAGE(p + 1, buf ^ 1); // other buffer; prev readers done at barrier
    ISSUE(p, 1, wa1, wb1);
    CONSUME(p, buf, 0, wa0, wb0);
    if (p < 3) ISSUE(p + 1, 0, wa0, wb0);
    CONSUME(p, buf, 1, wa1, wb1);
    __syncthreads();                  // buf consumed; buf^1 staged & visible
  }

  // per-i-block partial sums: part[ib][b][od] (wave-exclusive slice)
#pragma unroll
  for (int bt = 0; bt < 2; ++bt) {
    const int b = ccol + (bt << 4);
    float* pp = part + (((size_t)((ib << 5) + b)) << 11) + (ob << 6)
              + ((w << 4) + crow);
    float4 t; t.x = sacc[bt][0]; t.y = sacc[bt][1];
    t.z = sacc[bt][2]; t.w = sacc[bt][3];
    *(float4*)pp = t;
  }
}

// Reduce partials over 64 chunks -> s[b,o,:], squash -> vout[b][o][d].
__global__ __launch_bounds__(256) void k_reduce(
    const float* __restrict__ part, float* __restrict__ vout, float scale) {
  const int tid  = threadIdx.x;
  const int lane = tid & 63;
  const int wid  = (blockIdx.x << 2) + (tid >> 6);
  const int o = wid & 63, b = wid >> 6;
  const int d = lane & 31, h = lane >> 5;
  float s = 0.f;
  for (int c = h; c < 64; c += 2)
    s += part[(((size_t)((c << 5) + b)) << 11) + (o << 5) + d];
  s += __shfl_xor(s, 32);
  s *= scale;
  float p = s * s;
#pragma unroll
  for (int off = 1; off < 32; off <<= 1) p += __shfl_xor(p, off);
  const float v = (p > 0.f) ? s * sqrtf(p) / (1.f + p) : 0.f;
  if (h == 0) vout[(((b << 6) + o) << 5) + d] = v;
}

// Routing pass: per (b,i): logits[o] = sum_d u*(v1[+v2]); softmax over o (64 lanes);
// partial s accumulation in registers; per-block LDS combine -> part[chunk][b][od].
// block <-> (b, chunk of 32 i); 4 waves x 8 i each. lane <-> o. U loads CACHED.
__global__ __launch_bounds__(256) void k_route(
    const unsigned short* __restrict__ U, const float* __restrict__ V1,
    const float* __restrict__ V2, float* __restrict__ part) {
  __shared__ float red[4][ODIM];   // 32 KiB
  const int tid   = threadIdx.x;
  const int lane  = tid & 63;
  const int w     = tid >> 6;
  const int b     = blockIdx.x >> 6;
  const int chunk = blockIdx.x & 63;
  const int o     = lane;

  float vs[32];
  {
    const float* vp = V1 + (((b << 6) + o) << 5);
#pragma unroll
    for (int j = 0; j < 8; ++j) {
      const float4 t = *(const float4*)(vp + (j << 2));
      vs[4*j+0] = t.x; vs[4*j+1] = t.y; vs[4*j+2] = t.z; vs[4*j+3] = t.w;
    }
    if (V2 != nullptr) {
      const float* vq = V2 + (((b << 6) + o) << 5);
#pragma unroll
      for (int j = 0; j < 8; ++j) {
        const float4 t = *(const float4*)(vq + (j << 2));
        vs[4*j+0] += t.x; vs[4*j+1] += t.y; vs[4*j+2] += t.z; vs[4*j+3] += t.w;
      }
    }
  }

  float pacc[32];
#pragma unroll
  for (int d = 0; d < 32; ++d) pacc[d] = 0.f;

  const int i0 = (chunk << 5) + (w << 3);
  const unsigned short* ub = U + (((size_t)b * NI) << 11);

  u32x4 q0, q1, q2, q3;   // prefetched 64B u-row slice for this lane's o
  {
    const u32x4* p = (const u32x4*)(ub + (((size_t)i0) << 11) + (o << 5));
    q0 = p[0]; q1 = p[1]; q2 = p[2]; q3 = p[3];
  }
  for (int ii = 0; ii < 8; ++ii) {
    const u32x4 c0 = q0, c1 = q1, c2 = q2, c3 = q3;
    if (ii < 7) {
      const u32x4* p = (const u32x4*)(ub + (((size_t)(i0 + ii + 1)) << 11) + (o << 5));
      q0 = p[0]; q1 = p[1]; q2 = p[2]; q3 = p[3];
    }
    float uf[32];
    uf[ 0]=bflo(c0.x); uf[ 1]=bfhi(c0.x); uf[ 2]=bflo(c0.y); uf[ 3]=bfhi(c0.y);
    uf[ 4]=bflo(c0.z); uf[ 5]=bfhi(c0.z); uf[ 6]=bflo(c0.w); uf[ 7]=bfhi(c0.w);
    uf[ 8]=bflo(c1.x); uf[ 9]=bfhi(c1.x); uf[10]=bflo(c1.y); uf[11]=bfhi(c1.y);
    uf[12]=bflo(c1.z); uf[13]=bfhi(c1.z); uf[14]=bflo(c1.w); uf[15]=bfhi(c1.w);
    uf[16]=bflo(c2.x); uf[17]=bfhi(c2.x); uf[18]=bflo(c2.y); uf[19]=bfhi(c2.y);
    uf[20]=bflo(c2.z); uf[21]=bfhi(c2.z); uf[22]=bflo(c2.w); uf[23]=bfhi(c2.w);
    uf[24]=bflo(c3.x); uf[25]=bfhi(c3.x); uf[26]=bflo(c3.y); uf[27]=bfhi(c3.y);
    uf[28]=bflo(c3.z); uf[29]=bfhi(c3.z); uf[30]=bflo(c3.w); uf[31]=bfhi(c3.w);

    float dotA = 0.f, dotB = 0.f;
#pragma unroll
    for (int d = 0; d < 16; ++d) {
      dotA = fmaf(uf[d], vs[d], dotA);
      dotB = fmaf(uf[d + 16], vs[d + 16], dotB);
    }
    const float dot = dotA + dotB;
    float m = dot;
#pragma unroll
    for (int off = 1; off < 64; off <<= 1) m = fmaxf(m, __shfl_xor(m, off));
    const float e = __expf(dot - m);
    float Z = e;
#pragma unroll
    for (int off = 1; off < 64; off <<= 1) Z += __shfl_xor(Z, off);
    const float c = e / Z;
#pragma unroll
    for (int d = 0; d < 32; ++d) pacc[d] = fmaf(c, uf[d], pacc[d]);
  }

#pragma unroll
  for (int j = 0; j < 8; ++j) {
    float4 t; t.x = pacc[4*j]; t.y = pacc[4*j+1]; t.z = pacc[4*j+2]; t.w = pacc[4*j+3];
    *(float4*)&red[w][(o << 5) + (j << 2)] = t;
  }
  __syncthreads();
  float* pout = part + (((size_t)((chunk << 5) + b)) << 11);
  for (int t = tid; t < ODIM; t += 256)
    pout[t] = red[0][t] + red[1][t] + red[2][t] + red[3][t];
}

extern "C" void kernel_launch(void* const* d_in, const int* in_sizes, int n_in,
                              void* d_out, int out_size, void* d_ws, size_t ws_size,
                              hipStream_t stream) {
  const float* X = (const float*)d_in[0];   // [32][2048][32]
  const float* W = (const float*)d_in[1];   // [64][2048][32][32]
  float* out = (float*)d_out;               // [32][64][32]
  char* ws = (char*)d_ws;

  // ws layout: u_hat bf16 256MiB | part fp32 16MiB | v1 | v2   (ws = 2 GiB)
  unsigned short* U = (unsigned short*)ws;
  float* part = (float*)(ws + ((size_t)268435456));
  float* v1   = (float*)(ws + ((size_t)268435456 + 16777216));
  float* v2   = v1 + 65536;

  // iter 1: u_hat + uniform-c partial sums fused
  k1_uhat<<<2048, 256, 0, stream>>>(W, X, U, part);
  k_reduce<<<512, 256, 0, stream>>>(part, v1, 1.f / 64.f);
  // iter 2: logits = u.v1
  k_route<<<2048, 256, 0, stream>>>(U, v1, nullptr, part);
  k_reduce<<<512, 256, 0, stream>>>(part, v2, 1.f);
  // iter 3: logits = u.v1 + u.v2 = u.(v1+v2)
  k_route<<<2048, 256, 0, stream>>>(U, v1, v2, part);
  k_reduce<<<512, 256, 0, stream>>>(part, out, 1.f);
}

// Round 15
// 330.756 us; speedup vs baseline: 1.1391x; 1.1391x over previous
//
#include <hip/hip_runtime.h>

// Capsule routing: B=32, N_IN=2048, IN_DIM=32, N_OUT=64, OUT_DIM=32, 3 iterations.
#define NI   2048
#define NO   64
#define DD   32
#define ODIM 2048   // NO*DD, the fused (o,d) axis

typedef short bf16x8 __attribute__((ext_vector_type(8)));
typedef float f32x4  __attribute__((ext_vector_type(4)));
typedef unsigned int u32x2 __attribute__((ext_vector_type(2)));
typedef unsigned int u32x4 __attribute__((ext_vector_type(4)));

__device__ __forceinline__ unsigned int cvt_pk_bf16(float lo, float hi) {
  unsigned int r;
  asm("v_cvt_pk_bf16_f32 %0, %1, %2" : "=v"(r) : "v"(lo), "v"(hi));
  return r;
}
__device__ __forceinline__ float bflo(unsigned int u) { return __uint_as_float(u << 16); }
__device__ __forceinline__ float bfhi(unsigned int u) { return __uint_as_float(u & 0xffff0000u); }

union BFPack { unsigned int u[4]; bf16x8 v; };

// LDS-only barrier (R11): waits ds ops but does not drain vmcnt.
__device__ __forceinline__ void barrier_lds_only() {
  asm volatile("s_waitcnt lgkmcnt(0)" ::: "memory");
  __builtin_amdgcn_sched_barrier(0);
  __builtin_amdgcn_s_barrier();
  __builtin_amdgcn_sched_barrier(0);
}

// K1 (R15): identical to R11 (best, 327.6us) EXCEPT LDS bank-conflict-free
// address maps (single variable; sync/order/traffic unchanged):
//  xlds: [b:32]x[i:8]x[4 slot], b-stride 528 B (bank+4/row), physical slot
//        = logical ^ (i&3). Old layout: STAGE b128 writes 8-way (i-stride
//        2048 == 0 mod 128B), CONSUME reads 4-way. New: both <=2-way (free).
//  olds: [row:256] stride 128 B, 16-B chunk XOR-swizzled by (b&7); writes
//        and WRITEOUT reads both 2-way (old: writes ok, reads ok, but kept
//        aligned & smaller). LDS 53.2->49.6 KB, still 3 blocks/CU.
__global__ __launch_bounds__(256) void k1_uhat(
    const float* __restrict__ W, const float* __restrict__ X,
    unsigned short* __restrict__ U, float* __restrict__ part) {
  __shared__ __attribute__((aligned(16))) char olds[32768];   // 256 rows x 128 B
  __shared__ __attribute__((aligned(16))) char xlds[16880];   // 32 x 528 B (+i*64)
  const int tid   = threadIdx.x;
  const int lane  = tid & 63;
  const int w     = tid >> 6;
  const int ob    = blockIdx.x & 31;   // 64-od block
  const int ib    = blockIdx.x >> 5;   // i-block of 32
  const int odq   = (ob << 2) + w;     // 16-od strip
  const int o     = odq >> 1;          // output capsule
  const int db    = (odq & 1) << 4;    // d base within o
  const int row16 = lane & 15;         // A row within 16
  const int kg    = lane >> 4;         // k-group
  const int k0    = kg << 3;           // k offset (8 contiguous)
  const int crow  = kg << 2;           // C/D row base [m89 verified]
  const int ccol  = lane & 15;         // C/D col
  const int odl   = (w << 4) + crow;   // od within 64-od block
  const int c16   = (w << 1) | (kg >> 1);  // 16-B od-chunk index of this lane
  const int sb    = tid >> 3;          // stage: b (0..31)
  const int sii   = tid & 7;           // stage: i within phase (0..7)

  f32x4 sacc[2];
  sacc[0] = f32x4{0.f, 0.f, 0.f, 0.f};
  sacc[1] = f32x4{0.f, 0.f, 0.f, 0.f};

  const float* wbase = W + (((size_t)o * NI) << 10) + ((db + row16) << 5) + k0;

  // Stage X[all b][phase 8 i][all k] -> xlds bf16. One (b,i) row per thread:
  // 8 coalesced float4 loads, cvt, 4 b128 LDS writes (slot ^= i&3 swizzle).
  auto STAGE = [&](int p) {
    const int i = (ib << 5) + (p << 3) + sii;
    const float4* xp = (const float4*)(X + (((size_t)(sb * NI + i)) << 5));
    float4 xv[8];
#pragma unroll
    for (int j = 0; j < 8; ++j) xv[j] = xp[j];
    char* xrow = xlds + sb * 528 + (sii << 6);
#pragma unroll
    for (int j = 0; j < 4; ++j) {
      u32x4 pk;
      pk.x = cvt_pk_bf16(xv[2*j].x,   xv[2*j].y);
      pk.y = cvt_pk_bf16(xv[2*j].z,   xv[2*j].w);
      pk.z = cvt_pk_bf16(xv[2*j+1].x, xv[2*j+1].y);
      pk.w = cvt_pk_bf16(xv[2*j+1].z, xv[2*j+1].w);
      *(u32x4*)(xrow + ((j ^ (sii & 3)) << 4)) = pk;
    }
  };

  // Issue W NT loads for a 4-i half-batch; pin the issue point.
  auto ISSUE = [&](int p, int h, f32x4* wa, f32x4* wb) {
    const int ia = (ib << 5) + (p << 3) + (h << 2);
#pragma unroll
    for (int j = 0; j < 4; ++j) {
      const f32x4* wp = (const f32x4*)(wbase + ((size_t)(ia + j) << 10));
      wa[j] = __builtin_nontemporal_load(wp);
      wb[j] = __builtin_nontemporal_load(wp + 1);
    }
    __builtin_amdgcn_sched_barrier(0);
  };

  // Consume a staged half-batch: A from W regs, B from xlds, 2 MFMA -> olds.
  auto CONSUME = [&](int h, const f32x4* wa, const f32x4* wb) {
#pragma unroll
    for (int j = 0; j < 4; ++j) {
      const int ii = (h << 2) + j;
      const int xs = ((kg ^ (ii & 3)) << 4) + (ii << 6);
      bf16x8 bx0 = *(const bf16x8*)(xlds + ccol * 528 + xs);
      bf16x8 bx1 = *(const bf16x8*)(xlds + (ccol + 16) * 528 + xs);
      BFPack af;
      af.u[0] = cvt_pk_bf16(wa[j].x, wa[j].y);
      af.u[1] = cvt_pk_bf16(wa[j].z, wa[j].w);
      af.u[2] = cvt_pk_bf16(wb[j].x, wb[j].y);
      af.u[3] = cvt_pk_bf16(wb[j].z, wb[j].w);
      {
        f32x4 d = __builtin_amdgcn_mfma_f32_16x16x32_bf16(
            af.v, bx0, f32x4{0.f, 0.f, 0.f, 0.f}, 0, 0, 0);
        sacc[0] += d;
        u32x2 pk; pk.x = cvt_pk_bf16(d[0], d[1]); pk.y = cvt_pk_bf16(d[2], d[3]);
        *(u32x2*)(olds + (((ii << 5) + ccol) << 7)
                  + ((c16 ^ (ccol & 7)) << 4) + ((kg & 1) << 3)) = pk;
      }
      {
        f32x4 d = __builtin_amdgcn_mfma_f32_16x16x32_bf16(
            af.v, bx1, f32x4{0.f, 0.f, 0.f, 0.f}, 0, 0, 0);
        sacc[1] += d;
        u32x2 pk; pk.x = cvt_pk_bf16(d[0], d[1]); pk.y = cvt_pk_bf16(d[2], d[3]);
        *(u32x2*)(olds + (((ii << 5) + ccol + 16) << 7)
                  + ((c16 ^ (ccol & 7)) << 4) + ((kg & 1) << 3)) = pk;
      }
    }
  };

  f32x4 wa0[4], wb0[4], wa1[4], wb1[4];
  STAGE(0);
  ISSUE(0, 0, wa0, wb0);
  barrier_lds_only();

  for (int p = 0; p < 4; ++p) {
    const int i0 = (ib << 5) + (p << 3);
    ISSUE(p, 1, wa1, wb1);
    CONSUME(0, wa0, wb0);
    if (p < 3) ISSUE(p + 1, 0, wa0, wb0);
    CONSUME(1, wa1, wb1);
    barrier_lds_only();              // olds complete; xlds fully consumed
    if (p < 3) STAGE(p + 1);         // overlaps U write-out (disjoint LDS)
    // Cooperative write-out: thread t covers 16B of u[b][i0+r][ob*64+od16*8..+8];
    // 8 consecutive threads = 128B contiguous -> full lines. Cached store
    // (R10: populates L2/L3 for route passes). Read physical chunk od16^(b&7)
    // -> logical chunk od16 (involution).
    {
      const int b    = tid >> 3;
      const int od16 = tid & 7;
#pragma unroll
      for (int r = 0; r < 8; ++r) {
        const u32x4 v = *(const u32x4*)(olds + (((r << 5) + b) << 7)
                                        + ((od16 ^ (b & 7)) << 4));
        const size_t goff = (((size_t)(b * NI + i0 + r)) << 11) + (ob << 6) + (od16 << 3);
        *(u32x4*)(U + goff) = v;
      }
    }
    barrier_lds_only();              // write-out read done; xlds(p+1) visible
  }

  // per-i-block partial sums: part[ib][b][od] (wave-exclusive slice)
#pragma unroll
  for (int bt = 0; bt < 2; ++bt) {
    const int b  = ccol + (bt << 4);
    const int od = (ob << 6) + odl;
    float* pp = part + (((size_t)((ib << 5) + b)) << 11) + od;
    float4 t; t.x = sacc[bt][0]; t.y = sacc[bt][1];
    t.z = sacc[bt][2]; t.w = sacc[bt][3];
    *(float4*)pp = t;
  }
}

// Reduce partials over 64 chunks -> s[b,o,:], squash -> vout[b][o][d].
__global__ __launch_bounds__(256) void k_reduce(
    const float* __restrict__ part, float* __restrict__ vout, float scale) {
  const int tid  = threadIdx.x;
  const int lane = tid & 63;
  const int wid  = (blockIdx.x << 2) + (tid >> 6);
  const int o = wid & 63, b = wid >> 6;
  const int d = lane & 31, h = lane >> 5;
  float s = 0.f;
  for (int c = h; c < 64; c += 2)
    s += part[(((size_t)((c << 5) + b)) << 11) + (o << 5) + d];
  s += __shfl_xor(s, 32);
  s *= scale;
  float p = s * s;
#pragma unroll
  for (int off = 1; off < 32; off <<= 1) p += __shfl_xor(p, off);
  const float v = (p > 0.f) ? s * sqrtf(p) / (1.f + p) : 0.f;
  if (h == 0) vout[(((b << 6) + o) << 5) + d] = v;
}

// Routing pass: per (b,i): logits[o] = sum_d u*(v1[+v2]); softmax over o (64 lanes);
// partial s accumulation in registers; per-block LDS combine -> part[chunk][b][od].
// block <-> (b, chunk of 32 i); 4 waves x 8 i each. lane <-> o. U loads CACHED.
__global__ __launch_bounds__(256) void k_route(
    const unsigned short* __restrict__ U, const float* __restrict__ V1,
    const float* __restrict__ V2, float* __restrict__ part) {
  __shared__ float red[4][ODIM];   // 32 KiB
  const int tid   = threadIdx.x;
  const int lane  = tid & 63;
  const int w     = tid >> 6;
  const int b     = blockIdx.x >> 6;
  const int chunk = blockIdx.x & 63;
  const int o     = lane;

  float vs[32];
  {
    const float* vp = V1 + (((b << 6) + o) << 5);
#pragma unroll
    for (int j = 0; j < 8; ++j) {
      const float4 t = *(const float4*)(vp + (j << 2));
      vs[4*j+0] = t.x; vs[4*j+1] = t.y; vs[4*j+2] = t.z; vs[4*j+3] = t.w;
    }
    if (V2 != nullptr) {
      const float* vq = V2 + (((b << 6) + o) << 5);
#pragma unroll
      for (int j = 0; j < 8; ++j) {
        const float4 t = *(const float4*)(vq + (j << 2));
        vs[4*j+0] += t.x; vs[4*j+1] += t.y; vs[4*j+2] += t.z; vs[4*j+3] += t.w;
      }
    }
  }

  float pacc[32];
#pragma unroll
  for (int d = 0; d < 32; ++d) pacc[d] = 0.f;

  const int i0 = (chunk << 5) + (w << 3);
  const unsigned short* ub = U + (((size_t)b * NI) << 11);

  u32x4 q0, q1, q2, q3;   // prefetched 64B u-row slice for this lane's o
  {
    const u32x4* p = (const u32x4*)(ub + (((size_t)i0) << 11) + (o << 5));
    q0 = p[0]; q1 = p[1]; q2 = p[2]; q3 = p[3];
  }
  for (int ii = 0; ii < 8; ++ii) {
    const u32x4 c0 = q0, c1 = q1, c2 = q2, c3 = q3;
    if (ii < 7) {
      const u32x4* p = (const u32x4*)(ub + (((size_t)(i0 + ii + 1)) << 11) + (o << 5));
      q0 = p[0]; q1 = p[1]; q2 = p[2]; q3 = p[3];
    }
    float uf[32];
    uf[ 0]=bflo(c0.x); uf[ 1]=bfhi(c0.x); uf[ 2]=bflo(c0.y); uf[ 3]=bfhi(c0.y);
    uf[ 4]=bflo(c0.z); uf[ 5]=bfhi(c0.z); uf[ 6]=bflo(c0.w); uf[ 7]=bfhi(c0.w);
    uf[ 8]=bflo(c1.x); uf[ 9]=bfhi(c1.x); uf[10]=bflo(c1.y); uf[11]=bfhi(c1.y);
    uf[12]=bflo(c1.z); uf[13]=bfhi(c1.z); uf[14]=bflo(c1.w); uf[15]=bfhi(c1.w);
    uf[16]=bflo(c2.x); uf[17]=bfhi(c2.x); uf[18]=bflo(c2.y); uf[19]=bfhi(c2.y);
    uf[20]=bflo(c2.z); uf[21]=bfhi(c2.z); uf[22]=bflo(c2.w); uf[23]=bfhi(c2.w);
    uf[24]=bflo(c3.x); uf[25]=bfhi(c3.x); uf[26]=bflo(c3.y); uf[27]=bfhi(c3.y);
    uf[28]=bflo(c3.z); uf[29]=bfhi(c3.z); uf[30]=bflo(c3.w); uf[31]=bfhi(c3.w);

    float dotA = 0.f, dotB = 0.f;
#pragma unroll
    for (int d = 0; d < 16; ++d) {
      dotA = fmaf(uf[d], vs[d], dotA);
      dotB = fmaf(uf[d + 16], vs[d + 16], dotB);
    }
    const float dot = dotA + dotB;
    float m = dot;
#pragma unroll
    for (int off = 1; off < 64; off <<= 1) m = fmaxf(m, __shfl_xor(m, off));
    const float e = __expf(dot - m);
    float Z = e;
#pragma unroll
    for (int off = 1; off < 64; off <<= 1) Z += __shfl_xor(Z, off);
    const float c = e / Z;
#pragma unroll
    for (int d = 0; d < 32; ++d) pacc[d] = fmaf(c, uf[d], pacc[d]);
  }

#pragma unroll
  for (int j = 0; j < 8; ++j) {
    float4 t; t.x = pacc[4*j]; t.y = pacc[4*j+1]; t.z = pacc[4*j+2]; t.w = pacc[4*j+3];
    *(float4*)&red[w][(o << 5) + (j << 2)] = t;
  }
  __syncthreads();
  float* pout = part + (((size_t)((chunk << 5) + b)) << 11);
  for (int t = tid; t < ODIM; t += 256)
    pout[t] = red[0][t] + red[1][t] + red[2][t] + red[3][t];
}

extern "C" void kernel_launch(void* const* d_in, const int* in_sizes, int n_in,
                              void* d_out, int out_size, void* d_ws, size_t ws_size,
                              hipStream_t stream) {
  const float* X = (const float*)d_in[0];   // [32][2048][32]
  const float* W = (const float*)d_in[1];   // [64][2048][32][32]
  float* out = (float*)d_out;               // [32][64][32]
  char* ws = (char*)d_ws;

  // ws layout: u_hat bf16 256MiB | part fp32 16MiB | v1 | v2   (ws = 2 GiB)
  unsigned short* U = (unsigned short*)ws;
  float* part = (float*)(ws + ((size_t)268435456));
  float* v1   = (float*)(ws + ((size_t)268435456 + 16777216));
  float* v2   = v1 + 65536;

  // iter 1: u_hat + uniform-c partial sums fused
  k1_uhat<<<2048, 256, 0, stream>>>(W, X, U, part);
  k_reduce<<<512, 256, 0, stream>>>(part, v1, 1.f / 64.f);
  // iter 2: logits = u.v1
  k_route<<<2048, 256, 0, stream>>>(U, v1, nullptr, part);
  k_reduce<<<512, 256, 0, stream>>>(part, v2, 1.f);
  // iter 3: logits = u.v1 + u.v2 = u.(v1+v2)
  k_route<<<2048, 256, 0, stream>>>(U, v1, v2, part);
  k_reduce<<<512, 256, 0, stream>>>(part, out, 1.f);
}

// Round 16
// 277.376 us; speedup vs baseline: 1.3583x; 1.1924x over previous
//
#include <hip/hip_runtime.h>
#include <hip/hip_fp8.h>

// Capsule routing: B=32, N_IN=2048, IN_DIM=32, N_OUT=64, OUT_DIM=32, 3 iterations.
#define NI   2048
#define NO   64
#define DD   32
#define ODIM 2048   // NO*DD, the fused (o,d) axis

typedef short bf16x8 __attribute__((ext_vector_type(8)));
typedef float f32x4  __attribute__((ext_vector_type(4)));
typedef float f32x2  __attribute__((ext_vector_type(2)));
typedef unsigned int u32x2 __attribute__((ext_vector_type(2)));
typedef unsigned int u32x4 __attribute__((ext_vector_type(4)));

__device__ __forceinline__ unsigned int cvt_pk_bf16(float lo, float hi) {
  unsigned int r;
  asm("v_cvt_pk_bf16_f32 %0, %1, %2" : "=v"(r) : "v"(lo), "v"(hi));
  return r;
}

// fp8 e4m3 (OCP) pack/unpack; HW path on gfx950, header fallback otherwise.
__device__ __forceinline__ unsigned int pack4_fp8(float a, float b, float c, float d) {
#if __has_builtin(__builtin_amdgcn_cvt_pk_fp8_f32)
  unsigned int u = __builtin_amdgcn_cvt_pk_fp8_f32(a, b, 0, false);
  u = __builtin_amdgcn_cvt_pk_fp8_f32(c, d, u, true);
  return u;
#else
  __hip_fp8_e4m3 qa(a), qb(b), qc(c), qd(d);
  return (unsigned int)qa.__x | ((unsigned int)qb.__x << 8)
       | ((unsigned int)qc.__x << 16) | ((unsigned int)qd.__x << 24);
#endif
}
__device__ __forceinline__ void unpack4_fp8(unsigned int u, float* f) {
#if __has_builtin(__builtin_amdgcn_cvt_pk_f32_fp8)
  f32x2 lo = __builtin_amdgcn_cvt_pk_f32_fp8(u, false);
  f32x2 hi = __builtin_amdgcn_cvt_pk_f32_fp8(u, true);
  f[0] = lo.x; f[1] = lo.y; f[2] = hi.x; f[3] = hi.y;
#else
  __hip_fp8_e4m3 t;
  t.__x = (unsigned char)(u);        f[0] = (float)t;
  t.__x = (unsigned char)(u >> 8);   f[1] = (float)t;
  t.__x = (unsigned char)(u >> 16);  f[2] = (float)t;
  t.__x = (unsigned char)(u >> 24);  f[3] = (float)t;
#endif
}

// LDS-only barrier (R11): waits ds ops but does not drain vmcnt.
__device__ __forceinline__ void barrier_lds_only() {
  asm volatile("s_waitcnt lgkmcnt(0)" ::: "memory");
  __builtin_amdgcn_sched_barrier(0);
  __builtin_amdgcn_s_barrier();
  __builtin_amdgcn_sched_barrier(0);
}

// K1 (R16): = R11 (best, 327.6us) with U stored as FP8 e4m3 instead of bf16.
// Volume lever: U 268->134 MB written, routes read 134 MB each (was 268),
// and U now fits in HALF of L3 -> iter-3 mostly L3-resident. v1 stays exact
// (fp32 part path). olds rows: 64 B payload in 72-B rows (<=2-way banks).
// LDS 34.8 KB -> 4 blocks/CU (was 3). Sync structure byte-identical to R11.
__global__ __launch_bounds__(256) void k1_uhat(
    const float* __restrict__ W, const float* __restrict__ X,
    unsigned char* __restrict__ U, float* __restrict__ part) {
  __shared__ __attribute__((aligned(16))) char olds[256 * 72];            // 18,432 B
  __shared__ __attribute__((aligned(16))) unsigned short xlds[8][32][32]; // 16,384 B
  const int tid   = threadIdx.x;
  const int lane  = tid & 63;
  const int w     = tid >> 6;
  const int ob    = blockIdx.x & 31;   // 64-od block
  const int ib    = blockIdx.x >> 5;   // i-block of 32
  const int odq   = (ob << 2) + w;     // 16-od strip
  const int o     = odq >> 1;          // output capsule
  const int db    = (odq & 1) << 4;    // d base within o
  const int row16 = lane & 15;         // A row within 16
  const int kg    = lane >> 4;         // k-group
  const int k0    = kg << 3;           // k offset (8 contiguous)
  const int crow  = kg << 2;           // C/D row base [m89 verified]
  const int ccol  = lane & 15;         // C/D col
  const int odl   = (w << 4) + crow;   // od within 64-od block (= byte off, fp8)
  const int sb    = tid >> 3;          // stage: b (0..31)
  const int sii   = tid & 7;           // stage: i within phase (0..7)
  const int xslot = (kg ^ (ccol & 3)) << 3;  // swizzled k-slot for consume reads

  f32x4 sacc[2];
  sacc[0] = f32x4{0.f, 0.f, 0.f, 0.f};
  sacc[1] = f32x4{0.f, 0.f, 0.f, 0.f};

  const float* wbase = W + (((size_t)o * NI) << 10) + ((db + row16) << 5) + k0;

  // Stage X[all b][phase 8 i][all k] -> xlds bf16. One (b,i) row per thread.
  auto STAGE = [&](int p) {
    const int i = (ib << 5) + (p << 3) + sii;
    const float4* xp = (const float4*)(X + (((size_t)(sb * NI + i)) << 5));
    float4 xv[8];
#pragma unroll
    for (int j = 0; j < 8; ++j) xv[j] = xp[j];
#pragma unroll
    for (int j = 0; j < 4; ++j) {
      u32x4 pk;
      pk.x = cvt_pk_bf16(xv[2*j].x,   xv[2*j].y);
      pk.y = cvt_pk_bf16(xv[2*j].z,   xv[2*j].w);
      pk.z = cvt_pk_bf16(xv[2*j+1].x, xv[2*j+1].y);
      pk.w = cvt_pk_bf16(xv[2*j+1].z, xv[2*j+1].w);
      *(u32x4*)&xlds[sii][sb][(j ^ (sb & 3)) << 3] = pk;
    }
  };

  // Issue W NT loads for a 4-i half-batch; pin the issue point.
  auto ISSUE = [&](int p, int h, f32x4* wa, f32x4* wb) {
    const int ia = (ib << 5) + (p << 3) + (h << 2);
#pragma unroll
    for (int j = 0; j < 4; ++j) {
      const f32x4* wp = (const f32x4*)(wbase + ((size_t)(ia + j) << 10));
      wa[j] = __builtin_nontemporal_load(wp);
      wb[j] = __builtin_nontemporal_load(wp + 1);
    }
    __builtin_amdgcn_sched_barrier(0);
  };

  // Consume a staged half-batch: A from W regs, B from xlds, 2 MFMA ->
  // fp8-pack -> olds (4 B per lane-MFMA at row*72 + odl; <=2-way banks).
  auto CONSUME = [&](int h, const f32x4* wa, const f32x4* wb) {
#pragma unroll
    for (int j = 0; j < 4; ++j) {
      const int ii = (h << 2) + j;
      bf16x8 bx0 = *(const bf16x8*)&xlds[ii][ccol][xslot];
      bf16x8 bx1 = *(const bf16x8*)&xlds[ii][ccol + 16][xslot];
      unsigned int afu[4];
      afu[0] = cvt_pk_bf16(wa[j].x, wa[j].y);
      afu[1] = cvt_pk_bf16(wa[j].z, wa[j].w);
      afu[2] = cvt_pk_bf16(wb[j].x, wb[j].y);
      afu[3] = cvt_pk_bf16(wb[j].z, wb[j].w);
      bf16x8 af;
      af[0] = (short)(afu[0] & 0xffff); af[1] = (short)(afu[0] >> 16);
      af[2] = (short)(afu[1] & 0xffff); af[3] = (short)(afu[1] >> 16);
      af[4] = (short)(afu[2] & 0xffff); af[5] = (short)(afu[2] >> 16);
      af[6] = (short)(afu[3] & 0xffff); af[7] = (short)(afu[3] >> 16);
      {
        f32x4 d = __builtin_amdgcn_mfma_f32_16x16x32_bf16(
            af, bx0, f32x4{0.f, 0.f, 0.f, 0.f}, 0, 0, 0);
        sacc[0] += d;
        *(unsigned int*)(olds + ((ii << 5) + ccol) * 72 + odl) =
            pack4_fp8(d[0], d[1], d[2], d[3]);
      }
      {
        f32x4 d = __builtin_amdgcn_mfma_f32_16x16x32_bf16(
            af, bx1, f32x4{0.f, 0.f, 0.f, 0.f}, 0, 0, 0);
        sacc[1] += d;
        *(unsigned int*)(olds + ((ii << 5) + ccol + 16) * 72 + odl) =
            pack4_fp8(d[0], d[1], d[2], d[3]);
      }
    }
  };

  f32x4 wa0[4], wb0[4], wa1[4], wb1[4];
  STAGE(0);
  ISSUE(0, 0, wa0, wb0);
  barrier_lds_only();

  for (int p = 0; p < 4; ++p) {
    const int i0 = (ib << 5) + (p << 3);
    ISSUE(p, 1, wa1, wb1);
    CONSUME(0, wa0, wb0);
    if (p < 3) ISSUE(p + 1, 0, wa0, wb0);
    CONSUME(1, wa1, wb1);
    barrier_lds_only();              // olds complete; xlds fully consumed
    if (p < 3) STAGE(p + 1);         // overlaps U write-out (disjoint LDS)
    // Cooperative write-out: thread t covers 8 B of u[b][i0+r][ob*64+od32*8..+8];
    // 8 consecutive threads = 64 B contiguous runs; cached stores (L2 merges
    // the matching half-line from the ob^1 blocks; populates L2/L3 for routes).
    {
      const int b    = tid >> 3;
      const int od32 = tid & 7;
#pragma unroll
      for (int r = 0; r < 8; ++r) {
        const u32x2 v = *(const u32x2*)(olds + ((r << 5) + b) * 72 + (od32 << 3));
        const size_t goff = (((size_t)(b * NI + i0 + r)) << 11) + (ob << 6) + (od32 << 3);
        *(u32x2*)(U + goff) = v;
      }
    }
    barrier_lds_only();              // write-out read done; xlds(p+1) visible
  }

  // per-i-block partial sums: part[ib][b][od] (wave-exclusive slice, fp32 —
  // v1 stays exact; fp8 only affects iter-2/3 logits and s-accumulation)
#pragma unroll
  for (int bt = 0; bt < 2; ++bt) {
    const int b  = ccol + (bt << 4);
    const int od = (ob << 6) + odl;
    float* pp = part + (((size_t)((ib << 5) + b)) << 11) + od;
    float4 t; t.x = sacc[bt][0]; t.y = sacc[bt][1];
    t.z = sacc[bt][2]; t.w = sacc[bt][3];
    *(float4*)pp = t;
  }
}

// Reduce partials over 64 chunks -> s[b,o,:], squash -> vout[b][o][d].
__global__ __launch_bounds__(256) void k_reduce(
    const float* __restrict__ part, float* __restrict__ vout, float scale) {
  const int tid  = threadIdx.x;
  const int lane = tid & 63;
  const int wid  = (blockIdx.x << 2) + (tid >> 6);
  const int o = wid & 63, b = wid >> 6;
  const int d = lane & 31, h = lane >> 5;
  float s = 0.f;
  for (int c = h; c < 64; c += 2)
    s += part[(((size_t)((c << 5) + b)) << 11) + (o << 5) + d];
  s += __shfl_xor(s, 32);
  s *= scale;
  float p = s * s;
#pragma unroll
  for (int off = 1; off < 32; off <<= 1) p += __shfl_xor(p, off);
  const float v = (p > 0.f) ? s * sqrtf(p) / (1.f + p) : 0.f;
  if (h == 0) vout[(((b << 6) + o) << 5) + d] = v;
}

// Routing pass: per (b,i): logits[o] = sum_d u*(v1[+v2]); softmax over o (64 lanes);
// partial s accumulation in registers; per-block LDS combine -> part[chunk][b][od].
// block <-> (b, chunk of 32 i); 4 waves x 8 i each. lane <-> o.
// U is FP8 e4m3: 32 B per lane per i (2x u32x4), HW cvt_pk_f32_fp8 decode.
__global__ __launch_bounds__(256) void k_route(
    const unsigned char* __restrict__ U, const float* __restrict__ V1,
    const float* __restrict__ V2, float* __restrict__ part) {
  __shared__ float red[4][ODIM];   // 32 KiB
  const int tid   = threadIdx.x;
  const int lane  = tid & 63;
  const int w     = tid >> 6;
  const int b     = blockIdx.x >> 6;
  const int chunk = blockIdx.x & 63;
  const int o     = lane;

  float vs[32];
  {
    const float* vp = V1 + (((b << 6) + o) << 5);
#pragma unroll
    for (int j = 0; j < 8; ++j) {
      const float4 t = *(const float4*)(vp + (j << 2));
      vs[4*j+0] = t.x; vs[4*j+1] = t.y; vs[4*j+2] = t.z; vs[4*j+3] = t.w;
    }
    if (V2 != nullptr) {
      const float* vq = V2 + (((b << 6) + o) << 5);
#pragma unroll
      for (int j = 0; j < 8; ++j) {
        const float4 t = *(const float4*)(vq + (j << 2));
        vs[4*j+0] += t.x; vs[4*j+1] += t.y; vs[4*j+2] += t.z; vs[4*j+3] += t.w;
      }
    }
  }

  float pacc[32];
#pragma unroll
  for (int d = 0; d < 32; ++d) pacc[d] = 0.f;

  const int i0 = (chunk << 5) + (w << 3);
  const unsigned char* ub = U + (((size_t)b * NI) << 11);

  u32x4 qa, qb;   // prefetched 32 B u-row slice (32 fp8) for this lane's o
  {
    const u32x4* p = (const u32x4*)(ub + (((size_t)i0) << 11) + (o << 5));
    qa = p[0]; qb = p[1];
  }
  for (int ii = 0; ii < 8; ++ii) {
    const u32x4 ca = qa, cb = qb;
    if (ii < 7) {
      const u32x4* p = (const u32x4*)(ub + (((size_t)(i0 + ii + 1)) << 11) + (o << 5));
      qa = p[0]; qb = p[1];
    }
    float uf[32];
    unpack4_fp8(ca.x, uf +  0); unpack4_fp8(ca.y, uf +  4);
    unpack4_fp8(ca.z, uf +  8); unpack4_fp8(ca.w, uf + 12);
    unpack4_fp8(cb.x, uf + 16); unpack4_fp8(cb.y, uf + 20);
    unpack4_fp8(cb.z, uf + 24); unpack4_fp8(cb.w, uf + 28);

    float dotA = 0.f, dotB = 0.f;
#pragma unroll
    for (int d = 0; d < 16; ++d) {
      dotA = fmaf(uf[d], vs[d], dotA);
      dotB = fmaf(uf[d + 16], vs[d + 16], dotB);
    }
    const float dot = dotA + dotB;
    float m = dot;
#pragma unroll
    for (int off = 1; off < 64; off <<= 1) m = fmaxf(m, __shfl_xor(m, off));
    const float e = __expf(dot - m);
    float Z = e;
#pragma unroll
    for (int off = 1; off < 64; off <<= 1) Z += __shfl_xor(Z, off);
    const float c = e / Z;
#pragma unroll
    for (int d = 0; d < 32; ++d) pacc[d] = fmaf(c, uf[d], pacc[d]);
  }

#pragma unroll
  for (int j = 0; j < 8; ++j) {
    float4 t; t.x = pacc[4*j]; t.y = pacc[4*j+1]; t.z = pacc[4*j+2]; t.w = pacc[4*j+3];
    *(float4*)&red[w][(o << 5) + (j << 2)] = t;
  }
  __syncthreads();
  float* pout = part + (((size_t)((chunk << 5) + b)) << 11);
  for (int t = tid; t < ODIM; t += 256)
    pout[t] = red[0][t] + red[1][t] + red[2][t] + red[3][t];
}

extern "C" void kernel_launch(void* const* d_in, const int* in_sizes, int n_in,
                              void* d_out, int out_size, void* d_ws, size_t ws_size,
                              hipStream_t stream) {
  const float* X = (const float*)d_in[0];   // [32][2048][32]
  const float* W = (const float*)d_in[1];   // [64][2048][32][32]
  float* out = (float*)d_out;               // [32][64][32]
  char* ws = (char*)d_ws;

  // ws layout: u_hat fp8 128MiB | part fp32 16MiB | v1 | v2   (ws = 2 GiB)
  unsigned char* U = (unsigned char*)ws;
  float* part = (float*)(ws + ((size_t)134217728));
  float* v1   = (float*)(ws + ((size_t)134217728 + 16777216));
  float* v2   = v1 + 65536;

  // iter 1: u_hat + uniform-c partial sums fused
  k1_uhat<<<2048, 256, 0, stream>>>(W, X, U, part);
  k_reduce<<<512, 256, 0, stream>>>(part, v1, 1.f / 64.f);
  // iter 2: logits = u.v1
  k_route<<<2048, 256, 0, stream>>>(U, v1, nullptr, part);
  k_reduce<<<512, 256, 0, stream>>>(part, v2, 1.f);
  // iter 3: logits = u.v1 + u.v2 = u.(v1+v2)
  k_route<<<2048, 256, 0, stream>>>(U, v1, v2, part);
  k_reduce<<<512, 256, 0, stream>>>(part, out, 1.f);
}